// Round 8
// baseline (245.982 us; speedup 1.0000x reference)
//
#include <hip/hip_runtime.h>
#include <cfloat>
#include <math.h>

#define D_IN 128
#define D_OUT 64
#define NEG_SLOPE 0.2f
#define RPW 16   // rows per wave in linear kernel
#define ROWF 96  // floats per hkv row: 64 f32 (hk) + 64 bf16 (hv) = 384 B

// bf16 pack (RNE) / unpack helpers --------------------------------------------
__device__ __forceinline__ unsigned short f2bf(float x) {
  union { float f; unsigned u; } a; a.f = x;
  unsigned r = a.u + 0x7FFFu + ((a.u >> 16) & 1u);
  return (unsigned short)(r >> 16);
}
__device__ __forceinline__ float4 unpack4(uint2 q) {
  union { unsigned u; float f; } t;
  float4 r;
  t.u = q.x << 16;          r.x = t.f;
  t.u = q.x & 0xFFFF0000u;  r.y = t.f;
  t.u = q.y << 16;          r.z = t.f;
  t.u = q.y & 0xFFFF0000u;  r.w = t.f;
  return r;
}

// ---------------------------------------------------------------------------
// Kernel A (fused K+V): H = X @ W + b.
// Row layout: hkv[r] = [64 f32 of hk | 64 bf16 of hv]  (384 B)
// blockIdx < nblk: key half (f32), else value half (bf16).
// lane = output column; wave owns 16 rows. X row data is wave-uniform and
// forced onto the SCALAR path (readfirstlane base -> s_load_dwordx4), so the
// per-quad broadcast costs no vector-memory bandwidth. W from LDS as
// lane-consecutive ds_read_b32 (conflict-free). FMA: acc(V) += x(S) * w(V).
// ---------------------------------------------------------------------------
__global__ __launch_bounds__(256) void linear_kernel(
    const float* __restrict__ Xk, const float* __restrict__ Xv,
    const float* __restrict__ Wk, const float* __restrict__ bk,
    const float* __restrict__ Wv, const float* __restrict__ bv,
    float* __restrict__ hkv, int R, int nblk) {
  const int which = (blockIdx.x >= nblk) ? 1 : 0;
  const int blk = blockIdx.x - which * nblk;
  const float* __restrict__ X = which ? Xv : Xk;
  const float* __restrict__ W = which ? Wv : Wk;
  const float* __restrict__ bias = which ? bv : bk;

  __shared__ float Wl[D_IN * D_OUT];  // 32 KB, [k][col]
  __shared__ float bl[D_OUT];
  for (int i = threadIdx.x; i < D_IN * D_OUT / 4; i += 256)
    reinterpret_cast<float4*>(Wl)[i] = reinterpret_cast<const float4*>(W)[i];
  if (threadIdx.x < D_OUT) bl[threadIdx.x] = bias[threadIdx.x];
  __syncthreads();

  const int wave = threadIdx.x >> 6;
  const int lane = threadIdx.x & 63;
  const int r0 = (blk * 4 + wave) * RPW;
  if (r0 >= R) return;

  const float blv = bl[lane];

  if (r0 + RPW <= R) {
    // uniform row base on the scalar path
    const int base = __builtin_amdgcn_readfirstlane(r0) * D_IN;
    const float* __restrict__ xb = X + base;

    float acc[RPW];
#pragma unroll
    for (int r = 0; r < RPW; ++r) acc[r] = blv;

#pragma unroll 2
    for (int k4 = 0; k4 < D_IN / 4; ++k4) {
      const float wk0 = Wl[(4 * k4 + 0) * D_OUT + lane];
      const float wk1 = Wl[(4 * k4 + 1) * D_OUT + lane];
      const float wk2 = Wl[(4 * k4 + 2) * D_OUT + lane];
      const float wk3 = Wl[(4 * k4 + 3) * D_OUT + lane];
#pragma unroll
      for (int r = 0; r < RPW; ++r) {
        const float4 xq =
            *reinterpret_cast<const float4*>(xb + r * D_IN + 4 * k4);
        acc[r] = fmaf(xq.x, wk0, acc[r]);
        acc[r] = fmaf(xq.y, wk1, acc[r]);
        acc[r] = fmaf(xq.z, wk2, acc[r]);
        acc[r] = fmaf(xq.w, wk3, acc[r]);
      }
    }
#pragma unroll
    for (int r = 0; r < RPW; ++r) {
      float* row = hkv + (size_t)(r0 + r) * ROWF;
      if (which == 0) {
        row[lane] = acc[r];
      } else {
        reinterpret_cast<unsigned short*>(row + D_OUT)[lane] = f2bf(acc[r]);
      }
    }
  } else {
    // rare tail: per-row scalar path
    for (int r = r0; r < R; ++r) {
      const float* xr = X + (size_t)r * D_IN;
      float acc = blv;
      for (int k = 0; k < D_IN; ++k) acc = fmaf(xr[k], Wl[k * D_OUT + lane], acc);
      float* row = hkv + (size_t)r * ROWF;
      if (which == 0) row[lane] = acc;
      else reinterpret_cast<unsigned short*>(row + D_OUT)[lane] = f2bf(acc);
    }
  }
}

// ---------------------------------------------------------------------------
// Kernel B: CSR row pointers from sorted dst. row_ptr[i] = lower_bound(dst, i)
// ---------------------------------------------------------------------------
__global__ void rowptr_kernel(const int* __restrict__ dst, int E, int N,
                              int* __restrict__ row_ptr) {
  int i = blockIdx.x * blockDim.x + threadIdx.x;
  if (i > N) return;
  int lo = 0, hi = E;
  while (lo < hi) {
    int mid = (lo + hi) >> 1;
    if (dst[mid] < i) lo = mid + 1; else hi = mid;
  }
  row_ptr[i] = lo;
}

// ---------------------------------------------------------------------------
// sum over each 16-lane row via DPP rotate-adds (pure VALU).
// ---------------------------------------------------------------------------
__device__ __forceinline__ float rowsum16(float p) {
  union { float f; int i; } u, v;
  u.f = p;
  v.i = __builtin_amdgcn_update_dpp(0, u.i, 0x121, 0xF, 0xF, true);  // row_ror:1
  u.f += v.f;
  v.i = __builtin_amdgcn_update_dpp(0, u.i, 0x122, 0xF, 0xF, true);  // row_ror:2
  u.f += v.f;
  v.i = __builtin_amdgcn_update_dpp(0, u.i, 0x124, 0xF, 0xF, true);  // row_ror:4
  u.f += v.f;
  v.i = __builtin_amdgcn_update_dpp(0, u.i, 0x128, 0xF, 0xF, true);  // row_ror:8
  u.f += v.f;
  return u.f;
}

struct SMState { float m, l; float4 a; };

__device__ __forceinline__ void sm_update(SMState& st, float p, float4 vs) {
  const float mn = fmaxf(st.m, p);
  const float sc = __expf(st.m - mn);
  const float a = __expf(p - mn);
  st.l = st.l * sc + a;
  st.a.x = st.a.x * sc + a * vs.x;
  st.a.y = st.a.y * sc + a * vs.y;
  st.a.z = st.a.z * sc + a * vs.z;
  st.a.w = st.a.w * sc + a * vs.w;
  st.m = mn;
}

__device__ __forceinline__ void sm_merge(SMState& d, const SMState& s) {
  const float mn = fmaxf(d.m, s.m);
  const float s1 = __expf(d.m - mn);
  const float s2 = __expf(s.m - mn);
  d.l = d.l * s1 + s.l * s2;
  d.a.x = d.a.x * s1 + s.a.x * s2;
  d.a.y = d.a.y * s1 + s.a.y * s2;
  d.a.z = d.a.z * s1 + s.a.z * s2;
  d.a.w = d.a.w * s1 + s.a.w * s2;
  d.m = mn;
}

__device__ __forceinline__ void sm_merge_xor(SMState& d, int off) {
  SMState s;
  s.m = __shfl_xor(d.m, off, 64);
  s.l = __shfl_xor(d.l, off, 64);
  s.a.x = __shfl_xor(d.a.x, off, 64);
  s.a.y = __shfl_xor(d.a.y, off, 64);
  s.a.z = __shfl_xor(d.a.z, off, 64);
  s.a.w = __shfl_xor(d.a.w, off, 64);
  sm_merge(d, s);
}

__device__ __forceinline__ void edge_proc(const float* __restrict__ hb, int s,
                                          int li, const float4& kd,
                                          SMState& st) {
  const float* row = hb + (size_t)s * ROWF;
  const float4 ks = reinterpret_cast<const float4*>(row)[li];
  const float4 vs = unpack4(reinterpret_cast<const uint2*>(row + D_OUT)[li]);
  float p = ks.x * kd.x + ks.y * kd.y + ks.z * kd.z + ks.w * kd.w;
  p = rowsum16(p);
  sm_update(st, p, vs);
}

// ---------------------------------------------------------------------------
// Kernel C: per-node segmented online-softmax aggregation, BOTH batches per
// wave. 4 groups of 16 lanes; per group 2 ILP states x 2 batches = 4
// independent chains. hk gathered f32 (exact scores), hv bf16.
// ---------------------------------------------------------------------------
__global__ __launch_bounds__(256) void aggregate_kernel(
    const float* __restrict__ hkv, const int* __restrict__ src,
    const int* __restrict__ row_ptr, float* __restrict__ out, int N) {
  const int node = blockIdx.x * 4 + (threadIdx.x >> 6);
  const int lane = threadIdx.x & 63;
  if (node >= N) return;
  const float* hb0 = hkv;
  const float* hb1 = hkv + (size_t)N * ROWF;

  const int li = lane & 15;  // dim-quad index
  const int g = lane >> 4;   // edge group

  const float4 kd0 = reinterpret_cast<const float4*>(hb0 + (size_t)node * ROWF)[li];
  const float4 kd1 = reinterpret_cast<const float4*>(hb1 + (size_t)node * ROWF)[li];
  const int e0 = row_ptr[node];
  const int e1 = row_ptr[node + 1];

  SMState A0 = {-FLT_MAX, 0.f, {0.f, 0.f, 0.f, 0.f}};
  SMState B0 = A0, A1 = A0, B1 = A0;

  int e = e0 + g;
  for (; e + 4 < e1; e += 8) {
    const int sA = src[e];
    const int sB = src[e + 4];
    edge_proc(hb0, sA, li, kd0, A0);
    edge_proc(hb1, sA, li, kd1, A1);
    edge_proc(hb0, sB, li, kd0, B0);
    edge_proc(hb1, sB, li, kd1, B1);
  }
  if (e < e1) {
    const int sA = src[e];
    edge_proc(hb0, sA, li, kd0, A0);
    edge_proc(hb1, sA, li, kd1, A1);
  }

  sm_merge(A0, B0);
  sm_merge(A1, B1);
  sm_merge_xor(A0, 16); sm_merge_xor(A0, 32);
  sm_merge_xor(A1, 16); sm_merge_xor(A1, 32);

  if (lane < 16) {
#pragma unroll
    for (int b = 0; b < 2; ++b) {
      const SMState& S = b ? A1 : A0;
      const float denom = (S.l == 0.f) ? 1.f : S.l;
      float4 o;
      o.x = S.a.x / denom; o.y = S.a.y / denom;
      o.z = S.a.z / denom; o.w = S.a.w / denom;
      o.x = (o.x >= 0.f) ? o.x : NEG_SLOPE * o.x;
      o.y = (o.y >= 0.f) ? o.y : NEG_SLOPE * o.y;
      o.z = (o.z >= 0.f) ? o.z : NEG_SLOPE * o.z;
      o.w = (o.w >= 0.f) ? o.w : NEG_SLOPE * o.w;
      *reinterpret_cast<float4*>(out + ((size_t)b * N + node) * D_OUT + 4 * lane) = o;
    }
  }
}

// ---------------------------------------------------------------------------
extern "C" void kernel_launch(void* const* d_in, const int* in_sizes, int n_in,
                              void* d_out, int out_size, void* d_ws,
                              size_t ws_size, hipStream_t stream) {
  const float* X_key   = (const float*)d_in[0];
  const float* X_value = (const float*)d_in[1];
  const float* Wk      = (const float*)d_in[2];
  const float* bk      = (const float*)d_in[3];
  const float* Wv      = (const float*)d_in[4];
  const float* bv      = (const float*)d_in[5];
  const int*   src     = (const int*)d_in[6];
  const int*   dst     = (const int*)d_in[7];
  float* out = (float*)d_out;

  const int B = 2;
  const int R = in_sizes[0] / D_IN;  // B*N rows
  const int N = R / B;
  const int E = in_sizes[6];

  // workspace: hkv [R][96] f32-units (64 f32 hk | 64 bf16 hv) | row_ptr
  float* hkv = (float*)d_ws;
  int* row_ptr = (int*)(hkv + (size_t)R * ROWF);

  const int blocksB = (N + 1 + 255) / 256;
  hipLaunchKernelGGL(rowptr_kernel, dim3(blocksB), dim3(256), 0, stream,
                     dst, E, N, row_ptr);
  const int wavesPerMat = (R + RPW - 1) / RPW;
  const int nblk = (wavesPerMat + 3) / 4;
  hipLaunchKernelGGL(linear_kernel, dim3(2 * nblk), dim3(256), 0, stream,
                     X_key, X_value, Wk, bk, Wv, bv, hkv, R, nblk);
  const int blocksC = (N + 3) / 4;  // one wave per node, both batches
  hipLaunchKernelGGL(aggregate_kernel, dim3(blocksC), dim3(256), 0, stream,
                     hkv, src, row_ptr, out, N);
}

// Round 9
// 152.537 us; speedup vs baseline: 1.6126x; 1.6126x over previous
//
#include <hip/hip_runtime.h>
#include <cfloat>
#include <math.h>

#define D_IN 128
#define D_OUT 64
#define NEG_SLOPE 0.2f
#define TM 64     // rows per block in linear kernel
#define ROWH 128  // ushorts per hkv row: 64 fp16 (hk) + 64 bf16 (hv) = 256 B

typedef _Float16 half4v __attribute__((ext_vector_type(4)));

// pack/unpack helpers ---------------------------------------------------------
__device__ __forceinline__ unsigned short f2bf(float x) {
  union { float f; unsigned u; } a; a.f = x;
  unsigned r = a.u + 0x7FFFu + ((a.u >> 16) & 1u);
  return (unsigned short)(r >> 16);
}
__device__ __forceinline__ unsigned short f2h(float x) {
  union { _Float16 h; unsigned short u; } c;
  c.h = (_Float16)x;  // RNE
  return c.u;
}
__device__ __forceinline__ float4 unpack_bf4(uint2 q) {
  union { unsigned u; float f; } t;
  float4 r;
  t.u = q.x << 16;          r.x = t.f;
  t.u = q.x & 0xFFFF0000u;  r.y = t.f;
  t.u = q.y << 16;          r.z = t.f;
  t.u = q.y & 0xFFFF0000u;  r.w = t.f;
  return r;
}
__device__ __forceinline__ float4 unpack_h4(uint2 q) {
  union { uint2 u; half4v h; } c; c.u = q;
  float4 r;
  r.x = (float)c.h[0]; r.y = (float)c.h[1];
  r.z = (float)c.h[2]; r.w = (float)c.h[3];
  return r;
}

// ---------------------------------------------------------------------------
// Kernel A: H = X @ W + b -> 16-bit halves of the hkv row.
// which==0: key -> fp16 at ushort offset 0; which==1: value -> bf16 at 64.
// Proven R3 register-tiled body: thread (tc=t&15, tr=t>>4) computes 4 rows x
// 4 cols; W in LDS [k][col] (b128 quad reads); X rows via L1-broadcast quads.
// ---------------------------------------------------------------------------
__global__ __launch_bounds__(256) void linear_kernel(
    const float* __restrict__ X, const float* __restrict__ W,
    const float* __restrict__ bias, unsigned short* __restrict__ hkv,
    int R, int which) {
  __shared__ float Wl[D_IN * D_OUT];  // 32 KB, [k][col]
  __shared__ float bl[D_OUT];
  for (int i = threadIdx.x; i < D_IN * D_OUT / 4; i += 256)
    reinterpret_cast<float4*>(Wl)[i] = reinterpret_cast<const float4*>(W)[i];
  if (threadIdx.x < D_OUT) bl[threadIdx.x] = bias[threadIdx.x];
  __syncthreads();

  const int tc = threadIdx.x & 15;   // col quad: cols 4*tc..4*tc+3
  const int tr = threadIdx.x >> 4;   // row quad
  const int r0 = blockIdx.x * TM + tr * 4;
  if (r0 >= R) return;
  const int uoff = which ? D_OUT : 0;

  const float4 bv4 = reinterpret_cast<float4*>(bl)[tc];
  float acc[4][4];
#pragma unroll
  for (int i = 0; i < 4; ++i) {
    acc[i][0] = bv4.x; acc[i][1] = bv4.y; acc[i][2] = bv4.z; acc[i][3] = bv4.w;
  }

  if (r0 + 4 <= R) {
    const float4* x0 = reinterpret_cast<const float4*>(X + (size_t)(r0 + 0) * D_IN);
    const float4* x1 = reinterpret_cast<const float4*>(X + (size_t)(r0 + 1) * D_IN);
    const float4* x2 = reinterpret_cast<const float4*>(X + (size_t)(r0 + 2) * D_IN);
    const float4* x3 = reinterpret_cast<const float4*>(X + (size_t)(r0 + 3) * D_IN);
    for (int k4 = 0; k4 < D_IN / 4; ++k4) {
      float4 xv[4];
      xv[0] = x0[k4]; xv[1] = x1[k4]; xv[2] = x2[k4]; xv[3] = x3[k4];
      const float4 w0 = reinterpret_cast<const float4*>(Wl + (k4 * 4 + 0) * D_OUT)[tc];
      const float4 w1 = reinterpret_cast<const float4*>(Wl + (k4 * 4 + 1) * D_OUT)[tc];
      const float4 w2 = reinterpret_cast<const float4*>(Wl + (k4 * 4 + 2) * D_OUT)[tc];
      const float4 w3 = reinterpret_cast<const float4*>(Wl + (k4 * 4 + 3) * D_OUT)[tc];
#pragma unroll
      for (int i = 0; i < 4; ++i) {
        acc[i][0] += xv[i].x * w0.x + xv[i].y * w1.x + xv[i].z * w2.x + xv[i].w * w3.x;
        acc[i][1] += xv[i].x * w0.y + xv[i].y * w1.y + xv[i].z * w2.y + xv[i].w * w3.y;
        acc[i][2] += xv[i].x * w0.z + xv[i].y * w1.z + xv[i].z * w2.z + xv[i].w * w3.z;
        acc[i][3] += xv[i].x * w0.w + xv[i].y * w1.w + xv[i].z * w2.w + xv[i].w * w3.w;
      }
    }
#pragma unroll
    for (int i = 0; i < 4; ++i) {
      ushort4 o;
      if (which == 0) {
        o.x = f2h(acc[i][0]); o.y = f2h(acc[i][1]);
        o.z = f2h(acc[i][2]); o.w = f2h(acc[i][3]);
      } else {
        o.x = f2bf(acc[i][0]); o.y = f2bf(acc[i][1]);
        o.z = f2bf(acc[i][2]); o.w = f2bf(acc[i][3]);
      }
      *reinterpret_cast<ushort4*>(
          hkv + (size_t)(r0 + i) * ROWH + uoff + 4 * tc) = o;
    }
  } else {
    // guarded tail (rows r0..R-1)
    for (int i = 0; i < 4; ++i) {
      const int r = r0 + i;
      if (r >= R) break;
      float a0 = bv4.x, a1 = bv4.y, a2 = bv4.z, a3 = bv4.w;
      const float4* xr = reinterpret_cast<const float4*>(X + (size_t)r * D_IN);
      for (int k4 = 0; k4 < D_IN / 4; ++k4) {
        const float4 xv = xr[k4];
        const float4 w0 = reinterpret_cast<const float4*>(Wl + (k4 * 4 + 0) * D_OUT)[tc];
        const float4 w1 = reinterpret_cast<const float4*>(Wl + (k4 * 4 + 1) * D_OUT)[tc];
        const float4 w2 = reinterpret_cast<const float4*>(Wl + (k4 * 4 + 2) * D_OUT)[tc];
        const float4 w3 = reinterpret_cast<const float4*>(Wl + (k4 * 4 + 3) * D_OUT)[tc];
        a0 += xv.x * w0.x + xv.y * w1.x + xv.z * w2.x + xv.w * w3.x;
        a1 += xv.x * w0.y + xv.y * w1.y + xv.z * w2.y + xv.w * w3.y;
        a2 += xv.x * w0.z + xv.y * w1.z + xv.z * w2.z + xv.w * w3.z;
        a3 += xv.x * w0.w + xv.y * w1.w + xv.z * w2.w + xv.w * w3.w;
      }
      ushort4 o;
      if (which == 0) {
        o.x = f2h(a0); o.y = f2h(a1); o.z = f2h(a2); o.w = f2h(a3);
      } else {
        o.x = f2bf(a0); o.y = f2bf(a1); o.z = f2bf(a2); o.w = f2bf(a3);
      }
      *reinterpret_cast<ushort4*>(hkv + (size_t)r * ROWH + uoff + 4 * tc) = o;
    }
  }
}

// ---------------------------------------------------------------------------
// Kernel B: CSR row pointers from sorted dst. row_ptr[i] = lower_bound(dst, i)
// ---------------------------------------------------------------------------
__global__ void rowptr_kernel(const int* __restrict__ dst, int E, int N,
                              int* __restrict__ row_ptr) {
  int i = blockIdx.x * blockDim.x + threadIdx.x;
  if (i > N) return;
  int lo = 0, hi = E;
  while (lo < hi) {
    int mid = (lo + hi) >> 1;
    if (dst[mid] < i) lo = mid + 1; else hi = mid;
  }
  row_ptr[i] = lo;
}

// ---------------------------------------------------------------------------
// sum over each 16-lane row via DPP rotate-adds (pure VALU).
// ---------------------------------------------------------------------------
__device__ __forceinline__ float rowsum16(float p) {
  union { float f; int i; } u, v;
  u.f = p;
  v.i = __builtin_amdgcn_update_dpp(0, u.i, 0x121, 0xF, 0xF, true);  // row_ror:1
  u.f += v.f;
  v.i = __builtin_amdgcn_update_dpp(0, u.i, 0x122, 0xF, 0xF, true);  // row_ror:2
  u.f += v.f;
  v.i = __builtin_amdgcn_update_dpp(0, u.i, 0x124, 0xF, 0xF, true);  // row_ror:4
  u.f += v.f;
  v.i = __builtin_amdgcn_update_dpp(0, u.i, 0x128, 0xF, 0xF, true);  // row_ror:8
  u.f += v.f;
  return u.f;
}

struct SMState { float m, l; float4 a; };

__device__ __forceinline__ void sm_update(SMState& st, float p, float4 vs) {
  const float mn = fmaxf(st.m, p);
  const float sc = __expf(st.m - mn);
  const float a = __expf(p - mn);
  st.l = st.l * sc + a;
  st.a.x = st.a.x * sc + a * vs.x;
  st.a.y = st.a.y * sc + a * vs.y;
  st.a.z = st.a.z * sc + a * vs.z;
  st.a.w = st.a.w * sc + a * vs.w;
  st.m = mn;
}

__device__ __forceinline__ void sm_merge(SMState& d, const SMState& s) {
  const float mn = fmaxf(d.m, s.m);
  const float s1 = __expf(d.m - mn);
  const float s2 = __expf(s.m - mn);
  d.l = d.l * s1 + s.l * s2;
  d.a.x = d.a.x * s1 + s.a.x * s2;
  d.a.y = d.a.y * s1 + s.a.y * s2;
  d.a.z = d.a.z * s1 + s.a.z * s2;
  d.a.w = d.a.w * s1 + s.a.w * s2;
  d.m = mn;
}

__device__ __forceinline__ void sm_merge_xor(SMState& d, int off) {
  SMState s;
  s.m = __shfl_xor(d.m, off, 64);
  s.l = __shfl_xor(d.l, off, 64);
  s.a.x = __shfl_xor(d.a.x, off, 64);
  s.a.y = __shfl_xor(d.a.y, off, 64);
  s.a.z = __shfl_xor(d.a.z, off, 64);
  s.a.w = __shfl_xor(d.a.w, off, 64);
  sm_merge(d, s);
}

__device__ __forceinline__ void edge_proc(const unsigned short* __restrict__ hb,
                                          int s, int li, const float4& kd,
                                          SMState& st) {
  const unsigned short* row = hb + (size_t)s * ROWH;
  const float4 ks = unpack_h4(reinterpret_cast<const uint2*>(row)[li]);
  const float4 vs = unpack_bf4(reinterpret_cast<const uint2*>(row + D_OUT)[li]);
  float p = ks.x * kd.x + ks.y * kd.y + ks.z * kd.z + ks.w * kd.w;
  p = rowsum16(p);
  sm_update(st, p, vs);
}

// ---------------------------------------------------------------------------
// Kernel C: per-node segmented online-softmax aggregation, BOTH batches per
// wave. 4 groups of 16 lanes; per group 2 ILP states x 2 batches = 4
// independent chains. hk fp16 (f32-accumulated scores), hv bf16; 256 B rows.
// ---------------------------------------------------------------------------
__global__ __launch_bounds__(256) void aggregate_kernel(
    const unsigned short* __restrict__ hkv, const int* __restrict__ src,
    const int* __restrict__ row_ptr, float* __restrict__ out, int N) {
  const int node = blockIdx.x * 4 + (threadIdx.x >> 6);
  const int lane = threadIdx.x & 63;
  if (node >= N) return;
  const unsigned short* hb0 = hkv;
  const unsigned short* hb1 = hkv + (size_t)N * ROWH;

  const int li = lane & 15;  // dim-quad index
  const int g = lane >> 4;   // edge group

  const float4 kd0 =
      unpack_h4(reinterpret_cast<const uint2*>(hb0 + (size_t)node * ROWH)[li]);
  const float4 kd1 =
      unpack_h4(reinterpret_cast<const uint2*>(hb1 + (size_t)node * ROWH)[li]);
  const int e0 = row_ptr[node];
  const int e1 = row_ptr[node + 1];

  SMState A0 = {-FLT_MAX, 0.f, {0.f, 0.f, 0.f, 0.f}};
  SMState B0 = A0, A1 = A0, B1 = A0;

  int e = e0 + g;
  for (; e + 4 < e1; e += 8) {
    const int sA = src[e];
    const int sB = src[e + 4];
    edge_proc(hb0, sA, li, kd0, A0);
    edge_proc(hb1, sA, li, kd1, A1);
    edge_proc(hb0, sB, li, kd0, B0);
    edge_proc(hb1, sB, li, kd1, B1);
  }
  if (e < e1) {
    const int sA = src[e];
    edge_proc(hb0, sA, li, kd0, A0);
    edge_proc(hb1, sA, li, kd1, A1);
  }

  sm_merge(A0, B0);
  sm_merge(A1, B1);
  sm_merge_xor(A0, 16); sm_merge_xor(A0, 32);
  sm_merge_xor(A1, 16); sm_merge_xor(A1, 32);

  if (lane < 16) {
#pragma unroll
    for (int b = 0; b < 2; ++b) {
      const SMState& S = b ? A1 : A0;
      const float denom = (S.l == 0.f) ? 1.f : S.l;
      float4 o;
      o.x = S.a.x / denom; o.y = S.a.y / denom;
      o.z = S.a.z / denom; o.w = S.a.w / denom;
      o.x = (o.x >= 0.f) ? o.x : NEG_SLOPE * o.x;
      o.y = (o.y >= 0.f) ? o.y : NEG_SLOPE * o.y;
      o.z = (o.z >= 0.f) ? o.z : NEG_SLOPE * o.z;
      o.w = (o.w >= 0.f) ? o.w : NEG_SLOPE * o.w;
      *reinterpret_cast<float4*>(out + ((size_t)b * N + node) * D_OUT + 4 * lane) = o;
    }
  }
}

// ---------------------------------------------------------------------------
extern "C" void kernel_launch(void* const* d_in, const int* in_sizes, int n_in,
                              void* d_out, int out_size, void* d_ws,
                              size_t ws_size, hipStream_t stream) {
  const float* X_key   = (const float*)d_in[0];
  const float* X_value = (const float*)d_in[1];
  const float* Wk      = (const float*)d_in[2];
  const float* bk      = (const float*)d_in[3];
  const float* Wv      = (const float*)d_in[4];
  const float* bv      = (const float*)d_in[5];
  const int*   src     = (const int*)d_in[6];
  const int*   dst     = (const int*)d_in[7];
  float* out = (float*)d_out;

  const int B = 2;
  const int R = in_sizes[0] / D_IN;  // B*N rows
  const int N = R / B;
  const int E = in_sizes[6];

  // workspace: hkv ushort[R][128] (64 fp16 hk | 64 bf16 hv, 256 B) | row_ptr
  unsigned short* hkv = (unsigned short*)d_ws;
  int* row_ptr = (int*)(hkv + (size_t)R * ROWH);

  const int blocksB = (N + 1 + 255) / 256;
  hipLaunchKernelGGL(rowptr_kernel, dim3(blocksB), dim3(256), 0, stream,
                     dst, E, N, row_ptr);
  const int blocksA = (R + TM - 1) / TM;
  hipLaunchKernelGGL(linear_kernel, dim3(blocksA), dim3(256), 0, stream,
                     X_key, Wk, bk, hkv, R, 0);
  hipLaunchKernelGGL(linear_kernel, dim3(blocksA), dim3(256), 0, stream,
                     X_value, Wv, bv, hkv, R, 1);
  const int blocksC = (N + 3) / 4;  // one wave per node, both batches
  hipLaunchKernelGGL(aggregate_kernel, dim3(blocksC), dim3(256), 0, stream,
                     hkv, src, row_ptr, out, N);
}

// Round 10
// 149.179 us; speedup vs baseline: 1.6489x; 1.0225x over previous
//
#include <hip/hip_runtime.h>
#include <cfloat>
#include <math.h>

#define D_IN 128
#define D_OUT 64
#define NEG_SLOPE 0.2f
#define TM 64     // rows per block in linear kernel
#define ROWH 128  // ushorts per hkv row: 64 fp16 (hk) + 64 bf16 (hv) = 256 B
#define LOG2E 1.4426950408889634f

typedef _Float16 half2v __attribute__((ext_vector_type(2)));
typedef _Float16 half4v __attribute__((ext_vector_type(4)));

// pack/unpack helpers ---------------------------------------------------------
__device__ __forceinline__ unsigned short f2bf(float x) {
  union { float f; unsigned u; } a; a.f = x;
  unsigned r = a.u + 0x7FFFu + ((a.u >> 16) & 1u);
  return (unsigned short)(r >> 16);
}
__device__ __forceinline__ unsigned short f2h(float x) {
  union { _Float16 h; unsigned short u; } c;
  c.h = (_Float16)x;  // RNE
  return c.u;
}
__device__ __forceinline__ float4 unpack_bf4(uint2 q) {
  union { unsigned u; float f; } t;
  float4 r;
  t.u = q.x << 16;          r.x = t.f;
  t.u = q.x & 0xFFFF0000u;  r.y = t.f;
  t.u = q.y << 16;          r.z = t.f;
  t.u = q.y & 0xFFFF0000u;  r.w = t.f;
  return r;
}
// fp16-pair dot with f32 accumulate: 2 ops via v_dot2_f32_f16 when available
__device__ __forceinline__ float hdot4(uint2 a, uint2 b) {
  union { unsigned u; half2v h; } al, ah, bl, bh;
  al.u = a.x; ah.u = a.y; bl.u = b.x; bh.u = b.y;
#if __has_builtin(__builtin_amdgcn_fdot2)
  return __builtin_amdgcn_fdot2(al.h, bl.h,
         __builtin_amdgcn_fdot2(ah.h, bh.h, 0.f, false), false);
#else
  return (float)al.h[0] * (float)bl.h[0] + (float)al.h[1] * (float)bl.h[1] +
         (float)ah.h[0] * (float)bh.h[0] + (float)ah.h[1] * (float)bh.h[1];
#endif
}

// ---------------------------------------------------------------------------
// Kernel A: H = X @ W + b -> 16-bit halves of the hkv row.
// which==0: key -> fp16 at ushort offset 0; which==1: value -> bf16 at 64.
// R3 register-tiled body: thread (tc,tr) computes 4 rows x 4 cols.
// ---------------------------------------------------------------------------
__global__ __launch_bounds__(256) void linear_kernel(
    const float* __restrict__ X, const float* __restrict__ W,
    const float* __restrict__ bias, unsigned short* __restrict__ hkv,
    int R, int which) {
  __shared__ float Wl[D_IN * D_OUT];  // 32 KB, [k][col]
  __shared__ float bl[D_OUT];
  for (int i = threadIdx.x; i < D_IN * D_OUT / 4; i += 256)
    reinterpret_cast<float4*>(Wl)[i] = reinterpret_cast<const float4*>(W)[i];
  if (threadIdx.x < D_OUT) bl[threadIdx.x] = bias[threadIdx.x];
  __syncthreads();

  const int tc = threadIdx.x & 15;   // col quad
  const int tr = threadIdx.x >> 4;   // row quad
  const int r0 = blockIdx.x * TM + tr * 4;
  if (r0 >= R) return;
  const int uoff = which ? D_OUT : 0;

  const float4 bv4 = reinterpret_cast<float4*>(bl)[tc];
  float acc[4][4];
#pragma unroll
  for (int i = 0; i < 4; ++i) {
    acc[i][0] = bv4.x; acc[i][1] = bv4.y; acc[i][2] = bv4.z; acc[i][3] = bv4.w;
  }

  if (r0 + 4 <= R) {
    const float4* x0 = reinterpret_cast<const float4*>(X + (size_t)(r0 + 0) * D_IN);
    const float4* x1 = reinterpret_cast<const float4*>(X + (size_t)(r0 + 1) * D_IN);
    const float4* x2 = reinterpret_cast<const float4*>(X + (size_t)(r0 + 2) * D_IN);
    const float4* x3 = reinterpret_cast<const float4*>(X + (size_t)(r0 + 3) * D_IN);
    for (int k4 = 0; k4 < D_IN / 4; ++k4) {
      float4 xv[4];
      xv[0] = x0[k4]; xv[1] = x1[k4]; xv[2] = x2[k4]; xv[3] = x3[k4];
      const float4 w0 = reinterpret_cast<const float4*>(Wl + (k4 * 4 + 0) * D_OUT)[tc];
      const float4 w1 = reinterpret_cast<const float4*>(Wl + (k4 * 4 + 1) * D_OUT)[tc];
      const float4 w2 = reinterpret_cast<const float4*>(Wl + (k4 * 4 + 2) * D_OUT)[tc];
      const float4 w3 = reinterpret_cast<const float4*>(Wl + (k4 * 4 + 3) * D_OUT)[tc];
#pragma unroll
      for (int i = 0; i < 4; ++i) {
        acc[i][0] += xv[i].x * w0.x + xv[i].y * w1.x + xv[i].z * w2.x + xv[i].w * w3.x;
        acc[i][1] += xv[i].x * w0.y + xv[i].y * w1.y + xv[i].z * w2.y + xv[i].w * w3.y;
        acc[i][2] += xv[i].x * w0.z + xv[i].y * w1.z + xv[i].z * w2.z + xv[i].w * w3.z;
        acc[i][3] += xv[i].x * w0.w + xv[i].y * w1.w + xv[i].z * w2.w + xv[i].w * w3.w;
      }
    }
#pragma unroll
    for (int i = 0; i < 4; ++i) {
      ushort4 o;
      if (which == 0) {
        o.x = f2h(acc[i][0]); o.y = f2h(acc[i][1]);
        o.z = f2h(acc[i][2]); o.w = f2h(acc[i][3]);
      } else {
        o.x = f2bf(acc[i][0]); o.y = f2bf(acc[i][1]);
        o.z = f2bf(acc[i][2]); o.w = f2bf(acc[i][3]);
      }
      *reinterpret_cast<ushort4*>(
          hkv + (size_t)(r0 + i) * ROWH + uoff + 4 * tc) = o;
    }
  } else {
    for (int i = 0; i < 4; ++i) {
      const int r = r0 + i;
      if (r >= R) break;
      float a0 = bv4.x, a1 = bv4.y, a2 = bv4.z, a3 = bv4.w;
      const float4* xr = reinterpret_cast<const float4*>(X + (size_t)r * D_IN);
      for (int k4 = 0; k4 < D_IN / 4; ++k4) {
        const float4 xv = xr[k4];
        const float4 w0 = reinterpret_cast<const float4*>(Wl + (k4 * 4 + 0) * D_OUT)[tc];
        const float4 w1 = reinterpret_cast<const float4*>(Wl + (k4 * 4 + 1) * D_OUT)[tc];
        const float4 w2 = reinterpret_cast<const float4*>(Wl + (k4 * 4 + 2) * D_OUT)[tc];
        const float4 w3 = reinterpret_cast<const float4*>(Wl + (k4 * 4 + 3) * D_OUT)[tc];
        a0 += xv.x * w0.x + xv.y * w1.x + xv.z * w2.x + xv.w * w3.x;
        a1 += xv.x * w0.y + xv.y * w1.y + xv.z * w2.y + xv.w * w3.y;
        a2 += xv.x * w0.z + xv.y * w1.z + xv.z * w2.z + xv.w * w3.z;
        a3 += xv.x * w0.w + xv.y * w1.w + xv.z * w2.w + xv.w * w3.w;
      }
      ushort4 o;
      if (which == 0) {
        o.x = f2h(a0); o.y = f2h(a1); o.z = f2h(a2); o.w = f2h(a3);
      } else {
        o.x = f2bf(a0); o.y = f2bf(a1); o.z = f2bf(a2); o.w = f2bf(a3);
      }
      *reinterpret_cast<ushort4*>(hkv + (size_t)r * ROWH + uoff + 4 * tc) = o;
    }
  }
}

// ---------------------------------------------------------------------------
// Kernel B: CSR row pointers from sorted dst. row_ptr[i] = lower_bound(dst, i)
// ---------------------------------------------------------------------------
__global__ void rowptr_kernel(const int* __restrict__ dst, int E, int N,
                              int* __restrict__ row_ptr) {
  int i = blockIdx.x * blockDim.x + threadIdx.x;
  if (i > N) return;
  int lo = 0, hi = E;
  while (lo < hi) {
    int mid = (lo + hi) >> 1;
    if (dst[mid] < i) lo = mid + 1; else hi = mid;
  }
  row_ptr[i] = lo;
}

// ---------------------------------------------------------------------------
// sum over each 16-lane row via DPP rotate-adds (pure VALU).
// ---------------------------------------------------------------------------
__device__ __forceinline__ float rowsum16(float p) {
  union { float f; int i; } u, v;
  u.f = p;
  v.i = __builtin_amdgcn_update_dpp(0, u.i, 0x121, 0xF, 0xF, true);  // row_ror:1
  u.f += v.f;
  v.i = __builtin_amdgcn_update_dpp(0, u.i, 0x122, 0xF, 0xF, true);  // row_ror:2
  u.f += v.f;
  v.i = __builtin_amdgcn_update_dpp(0, u.i, 0x124, 0xF, 0xF, true);  // row_ror:4
  u.f += v.f;
  v.i = __builtin_amdgcn_update_dpp(0, u.i, 0x128, 0xF, 0xF, true);  // row_ror:8
  u.f += v.f;
  return u.f;
}

// online-softmax state, log2 domain (weights = exp2(pl - m))
struct SMState { float m, l; float4 a; };

// branchy update: common path = 1 exp2 + 5 fma; rescale only on new max
// (pl is uniform across the 16-lane group -> clean exec-mask branch)
__device__ __forceinline__ void sm_update(SMState& st, float pl,
                                          const float4& vs) {
  if (pl > st.m) {
    const float sc = exp2f(st.m - pl);  // first edge: exp2(-inf) = 0
    st.l *= sc;
    st.a.x *= sc; st.a.y *= sc; st.a.z *= sc; st.a.w *= sc;
    st.m = pl;
  }
  const float a = exp2f(pl - st.m);
  st.l += a;
  st.a.x = fmaf(a, vs.x, st.a.x);
  st.a.y = fmaf(a, vs.y, st.a.y);
  st.a.z = fmaf(a, vs.z, st.a.z);
  st.a.w = fmaf(a, vs.w, st.a.w);
}

__device__ __forceinline__ void sm_merge(SMState& d, const SMState& s) {
  const float mn = fmaxf(d.m, s.m);
  const float s1 = exp2f(d.m - mn);
  const float s2 = exp2f(s.m - mn);
  d.l = d.l * s1 + s.l * s2;
  d.a.x = d.a.x * s1 + s.a.x * s2;
  d.a.y = d.a.y * s1 + s.a.y * s2;
  d.a.z = d.a.z * s1 + s.a.z * s2;
  d.a.w = d.a.w * s1 + s.a.w * s2;
  d.m = mn;
}

__device__ __forceinline__ void sm_merge_xor(SMState& d, int off) {
  SMState s;
  s.m = __shfl_xor(d.m, off, 64);
  s.l = __shfl_xor(d.l, off, 64);
  s.a.x = __shfl_xor(d.a.x, off, 64);
  s.a.y = __shfl_xor(d.a.y, off, 64);
  s.a.z = __shfl_xor(d.a.z, off, 64);
  s.a.w = __shfl_xor(d.a.w, off, 64);
  sm_merge(d, s);
}

// ---------------------------------------------------------------------------
// Kernel C: per-node segmented online-softmax aggregation, BOTH batches per
// wave. 4 groups of 16 lanes; per group 2 ILP states x 2 batches. Per
// iteration all 8 row-loads are issued BEFORE any (branchy) compute.
// hk fp16 via v_dot2_f32_f16; hv bf16; 256 B rows; exp2-domain softmax.
// ---------------------------------------------------------------------------
__global__ __launch_bounds__(256) void aggregate_kernel(
    const unsigned short* __restrict__ hkv, const int* __restrict__ src,
    const int* __restrict__ row_ptr, float* __restrict__ out, int N) {
  const int node = blockIdx.x * 4 + (threadIdx.x >> 6);
  const int lane = threadIdx.x & 63;
  if (node >= N) return;
  const unsigned short* hb0 = hkv;
  const unsigned short* hb1 = hkv + (size_t)N * ROWH;

  const int li = lane & 15;  // dim-quad index (uint2 granule)
  const int g = lane >> 4;   // edge group

  const uint2 kd0 = reinterpret_cast<const uint2*>(hb0 + (size_t)node * ROWH)[li];
  const uint2 kd1 = reinterpret_cast<const uint2*>(hb1 + (size_t)node * ROWH)[li];
  const int e0 = row_ptr[node];
  const int e1 = row_ptr[node + 1];

  SMState A0 = {-FLT_MAX, 0.f, {0.f, 0.f, 0.f, 0.f}};
  SMState B0 = A0, A1 = A0, B1 = A0;

  int e = e0 + g;
  for (; e + 4 < e1; e += 8) {
    const int sA = src[e];
    const int sB = src[e + 4];
    // issue all 8 loads up front (kept in flight across the compute)
    const uint2* rA0 = reinterpret_cast<const uint2*>(hb0 + (size_t)sA * ROWH);
    const uint2* rA1 = reinterpret_cast<const uint2*>(hb1 + (size_t)sA * ROWH);
    const uint2* rB0 = reinterpret_cast<const uint2*>(hb0 + (size_t)sB * ROWH);
    const uint2* rB1 = reinterpret_cast<const uint2*>(hb1 + (size_t)sB * ROWH);
    const uint2 kA0 = rA0[li], vA0 = rA0[16 + li];
    const uint2 kA1 = rA1[li], vA1 = rA1[16 + li];
    const uint2 kB0 = rB0[li], vB0 = rB0[16 + li];
    const uint2 kB1 = rB1[li], vB1 = rB1[16 + li];

    const float plA0 = rowsum16(hdot4(kA0, kd0)) * LOG2E;
    const float plA1 = rowsum16(hdot4(kA1, kd1)) * LOG2E;
    const float plB0 = rowsum16(hdot4(kB0, kd0)) * LOG2E;
    const float plB1 = rowsum16(hdot4(kB1, kd1)) * LOG2E;

    sm_update(A0, plA0, unpack_bf4(vA0));
    sm_update(A1, plA1, unpack_bf4(vA1));
    sm_update(B0, plB0, unpack_bf4(vB0));
    sm_update(B1, plB1, unpack_bf4(vB1));
  }
  if (e < e1) {
    const int sA = src[e];
    const uint2* rA0 = reinterpret_cast<const uint2*>(hb0 + (size_t)sA * ROWH);
    const uint2* rA1 = reinterpret_cast<const uint2*>(hb1 + (size_t)sA * ROWH);
    const uint2 kA0 = rA0[li], vA0 = rA0[16 + li];
    const uint2 kA1 = rA1[li], vA1 = rA1[16 + li];
    const float plA0 = rowsum16(hdot4(kA0, kd0)) * LOG2E;
    const float plA1 = rowsum16(hdot4(kA1, kd1)) * LOG2E;
    sm_update(A0, plA0, unpack_bf4(vA0));
    sm_update(A1, plA1, unpack_bf4(vA1));
  }

  sm_merge(A0, B0);
  sm_merge(A1, B1);
  sm_merge_xor(A0, 16); sm_merge_xor(A0, 32);
  sm_merge_xor(A1, 16); sm_merge_xor(A1, 32);

  if (lane < 16) {
#pragma unroll
    for (int b = 0; b < 2; ++b) {
      const SMState& S = b ? A1 : A0;
      const float denom = (S.l == 0.f) ? 1.f : S.l;
      float4 o;
      o.x = S.a.x / denom; o.y = S.a.y / denom;
      o.z = S.a.z / denom; o.w = S.a.w / denom;
      o.x = (o.x >= 0.f) ? o.x : NEG_SLOPE * o.x;
      o.y = (o.y >= 0.f) ? o.y : NEG_SLOPE * o.y;
      o.z = (o.z >= 0.f) ? o.z : NEG_SLOPE * o.z;
      o.w = (o.w >= 0.f) ? o.w : NEG_SLOPE * o.w;
      *reinterpret_cast<float4*>(out + ((size_t)b * N + node) * D_OUT + 4 * lane) = o;
    }
  }
}

// ---------------------------------------------------------------------------
extern "C" void kernel_launch(void* const* d_in, const int* in_sizes, int n_in,
                              void* d_out, int out_size, void* d_ws,
                              size_t ws_size, hipStream_t stream) {
  const float* X_key   = (const float*)d_in[0];
  const float* X_value = (const float*)d_in[1];
  const float* Wk      = (const float*)d_in[2];
  const float* bk      = (const float*)d_in[3];
  const float* Wv      = (const float*)d_in[4];
  const float* bv      = (const float*)d_in[5];
  const int*   src     = (const int*)d_in[6];
  const int*   dst     = (const int*)d_in[7];
  float* out = (float*)d_out;

  const int B = 2;
  const int R = in_sizes[0] / D_IN;  // B*N rows
  const int N = R / B;
  const int E = in_sizes[6];

  // workspace: hkv ushort[R][128] (64 fp16 hk | 64 bf16 hv, 256 B) | row_ptr
  unsigned short* hkv = (unsigned short*)d_ws;
  int* row_ptr = (int*)(hkv + (size_t)R * ROWH);

  const int blocksB = (N + 1 + 255) / 256;
  hipLaunchKernelGGL(rowptr_kernel, dim3(blocksB), dim3(256), 0, stream,
                     dst, E, N, row_ptr);
  const int blocksA = (R + TM - 1) / TM;
  hipLaunchKernelGGL(linear_kernel, dim3(blocksA), dim3(256), 0, stream,
                     X_key, Wk, bk, hkv, R, 0);
  hipLaunchKernelGGL(linear_kernel, dim3(blocksA), dim3(256), 0, stream,
                     X_value, Wv, bv, hkv, R, 1);
  const int blocksC = (N + 3) / 4;  // one wave per node, both batches
  hipLaunchKernelGGL(aggregate_kernel, dim3(blocksC), dim3(256), 0, stream,
                     hkv, src, row_ptr, out, N);
}

// Round 11
// 99.959 us; speedup vs baseline: 2.4608x; 1.4924x over previous
//
#include <hip/hip_runtime.h>
#include <cfloat>
#include <math.h>

#define D_IN 128
#define D_OUT 64
#define NEG_SLOPE 0.2f
#define ROWH 128  // ushorts per hkv row: 64 fp16 (hk) + 64 bf16 (hv) = 256 B
#define SQRT_LOG2E 1.2011224087864498f

typedef _Float16 half2v __attribute__((ext_vector_type(2)));
typedef _Float16 half8 __attribute__((ext_vector_type(8)));
typedef float f32x4 __attribute__((ext_vector_type(4)));

// pack/unpack helpers ---------------------------------------------------------
__device__ __forceinline__ unsigned short f2bf(float x) {
  union { float f; unsigned u; } a; a.f = x;
  unsigned r = a.u + 0x7FFFu + ((a.u >> 16) & 1u);
  return (unsigned short)(r >> 16);
}
__device__ __forceinline__ unsigned short f2h(float x) {
  union { _Float16 h; unsigned short u; } c;
  c.h = (_Float16)x;  // RNE
  return c.u;
}
__device__ __forceinline__ float4 unpack_bf4(uint2 q) {
  union { unsigned u; float f; } t;
  float4 r;
  t.u = q.x << 16;          r.x = t.f;
  t.u = q.x & 0xFFFF0000u;  r.y = t.f;
  t.u = q.y << 16;          r.z = t.f;
  t.u = q.y & 0xFFFF0000u;  r.w = t.f;
  return r;
}
// fp16-pair dot with f32 accumulate via v_dot2_f32_f16
__device__ __forceinline__ float hdot4(uint2 a, uint2 b) {
  union { unsigned u; half2v h; } al, ah, bl, bh;
  al.u = a.x; ah.u = a.y; bl.u = b.x; bh.u = b.y;
#if __has_builtin(__builtin_amdgcn_fdot2)
  return __builtin_amdgcn_fdot2(al.h, bl.h,
         __builtin_amdgcn_fdot2(ah.h, bh.h, 0.f, false), false);
#else
  return (float)al.h[0] * (float)bl.h[0] + (float)al.h[1] * (float)bl.h[1] +
         (float)ah.h[0] * (float)bh.h[0] + (float)ah.h[1] * (float)bh.h[1];
#endif
}

// ---------------------------------------------------------------------------
// Kernel P: pack W (f32) into per-lane MFMA B-fragments (fp16).
// Table entry (k0i, nt, lane) -> half8 of W[k0i*32 + (lane>>4)*8 + j]
// [nt*16 + (lane&15)], j=0..7. Wk is pre-scaled by sqrt(log2 e) so the
// gathered score dot is already in the exp2 domain.
// idx < 1024: Wk table; idx >= 1024: Wv table. 2048 entries x 16 B = 32 KB.
// ---------------------------------------------------------------------------
__global__ void bfrag_kernel(const float* __restrict__ Wk,
                             const float* __restrict__ Wv,
                             _Float16* __restrict__ bfrag) {
  const int idx = blockIdx.x * 256 + threadIdx.x;
  if (idx >= 2048) return;
  const int which = idx >> 10;
  const float* __restrict__ W = which ? Wv : Wk;
  const float scale = which ? 1.0f : SQRT_LOG2E;
  const int li = idx & 1023;
  const int lane = li & 63;
  const int nt = (li >> 6) & 3;
  const int k0i = li >> 8;
  const int col = nt * 16 + (lane & 15);
  const int kbase = k0i * 32 + (lane >> 4) * 8;
  half8 h;
#pragma unroll
  for (int j = 0; j < 8; ++j)
    h[j] = (_Float16)(W[(size_t)(kbase + j) * D_OUT + col] * scale);
  reinterpret_cast<half8*>(bfrag)[idx] = h;
}

// ---------------------------------------------------------------------------
// Kernel A: H = X @ W + b via mfma_f32_16x16x32_f16.
// One wave = 16 rows x 64 cols (4 col-tiles x 4 K-steps = 16 MFMAs).
// A-frag: lane holds X[r0+(lane&15)][k0+8*(lane>>4)+j] (f32 load + cvt).
// B-frags preloaded from the bfrag table (coalesced, L2-hot).
// C/D: col = lane&15 (+nt*16), row = r0 + (lane>>4)*4 + r   [m89 mapping]
// which==0 -> fp16 hk (pre-scaled by sqrt(log2e)); which==1 -> bf16 hv.
// ---------------------------------------------------------------------------
__global__ __launch_bounds__(256) void linear_mfma_kernel(
    const float* __restrict__ Xk, const float* __restrict__ Xv,
    const float* __restrict__ Wk, const float* __restrict__ bk,
    const float* __restrict__ Wv, const float* __restrict__ bv,
    const _Float16* __restrict__ bfrag, unsigned short* __restrict__ hkv,
    int R, int nblk) {
  const int which = (blockIdx.x >= nblk) ? 1 : 0;
  const int blk = blockIdx.x - which * nblk;
  const float* __restrict__ X = which ? Xv : Xk;
  const float* __restrict__ bias = which ? bv : bk;
  const float bscale = which ? 1.0f : SQRT_LOG2E;
  const int uoff = which ? D_OUT : 0;

  const int wave = threadIdx.x >> 6;
  const int lane = threadIdx.x & 63;
  const int r0 = (blk * 4 + wave) * 16;
  if (r0 >= R) return;
  const int rowi = lane & 15;
  const int kgrp = lane >> 4;

  if (r0 + 16 <= R) {
    const half8* btab =
        reinterpret_cast<const half8*>(bfrag) + (which ? 1024 : 0);
    half8 bf[4][4];
#pragma unroll
    for (int k0i = 0; k0i < 4; ++k0i)
#pragma unroll
      for (int nt = 0; nt < 4; ++nt)
        bf[k0i][nt] = btab[(k0i * 4 + nt) * 64 + lane];

    f32x4 acc[4];
#pragma unroll
    for (int nt = 0; nt < 4; ++nt) acc[nt] = (f32x4){0.f, 0.f, 0.f, 0.f};

    const float* xrow = X + (size_t)(r0 + rowi) * D_IN;
#pragma unroll
    for (int k0i = 0; k0i < 4; ++k0i) {
      const float4 x0 =
          *reinterpret_cast<const float4*>(xrow + k0i * 32 + kgrp * 8);
      const float4 x1 =
          *reinterpret_cast<const float4*>(xrow + k0i * 32 + kgrp * 8 + 4);
      half8 a;
      a[0] = (_Float16)x0.x; a[1] = (_Float16)x0.y;
      a[2] = (_Float16)x0.z; a[3] = (_Float16)x0.w;
      a[4] = (_Float16)x1.x; a[5] = (_Float16)x1.y;
      a[6] = (_Float16)x1.z; a[7] = (_Float16)x1.w;
#pragma unroll
      for (int nt = 0; nt < 4; ++nt)
        acc[nt] = __builtin_amdgcn_mfma_f32_16x16x32_f16(a, bf[k0i][nt],
                                                         acc[nt], 0, 0, 0);
    }
#pragma unroll
    for (int nt = 0; nt < 4; ++nt) {
      const int col = nt * 16 + rowi;
      const float bcol = bias[col] * bscale;
#pragma unroll
      for (int r = 0; r < 4; ++r) {
        const int row = r0 + kgrp * 4 + r;
        const float val = acc[nt][r] + bcol;
        hkv[(size_t)row * ROWH + uoff + col] =
            which ? f2bf(val) : f2h(val);
      }
    }
  } else {
    // tail rows (R%16 != 0 only): direct f32 dot, lane = column
    const float* __restrict__ W = which ? Wv : Wk;
    for (int r = r0; r < R; ++r) {
      const float* xr = X + (size_t)r * D_IN;
      float acc = bias[lane];
      for (int k = 0; k < D_IN; ++k)
        acc = fmaf(xr[k], W[(size_t)k * D_OUT + lane], acc);
      acc *= bscale;
      hkv[(size_t)r * ROWH + uoff + lane] = which ? f2bf(acc) : f2h(acc);
    }
  }
}

// ---------------------------------------------------------------------------
// Kernel B: CSR row pointers from sorted dst. row_ptr[i] = lower_bound(dst, i)
// ---------------------------------------------------------------------------
__global__ void rowptr_kernel(const int* __restrict__ dst, int E, int N,
                              int* __restrict__ row_ptr) {
  int i = blockIdx.x * blockDim.x + threadIdx.x;
  if (i > N) return;
  int lo = 0, hi = E;
  while (lo < hi) {
    int mid = (lo + hi) >> 1;
    if (dst[mid] < i) lo = mid + 1; else hi = mid;
  }
  row_ptr[i] = lo;
}

// ---------------------------------------------------------------------------
// sum over each 16-lane row via DPP rotate-adds (pure VALU).
// ---------------------------------------------------------------------------
__device__ __forceinline__ float rowsum16(float p) {
  union { float f; int i; } u, v;
  u.f = p;
  v.i = __builtin_amdgcn_update_dpp(0, u.i, 0x121, 0xF, 0xF, true);  // row_ror:1
  u.f += v.f;
  v.i = __builtin_amdgcn_update_dpp(0, u.i, 0x122, 0xF, 0xF, true);  // row_ror:2
  u.f += v.f;
  v.i = __builtin_amdgcn_update_dpp(0, u.i, 0x124, 0xF, 0xF, true);  // row_ror:4
  u.f += v.f;
  v.i = __builtin_amdgcn_update_dpp(0, u.i, 0x128, 0xF, 0xF, true);  // row_ror:8
  u.f += v.f;
  return u.f;
}

// online-softmax state, exp2 domain (hk pre-scaled so dot is log2-weighted)
struct SMState { float m, l; float4 a; };

__device__ __forceinline__ void sm_update(SMState& st, float pl,
                                          const float4& vs) {
  if (pl > st.m) {
    const float sc = exp2f(st.m - pl);  // first edge: exp2(-inf) = 0
    st.l *= sc;
    st.a.x *= sc; st.a.y *= sc; st.a.z *= sc; st.a.w *= sc;
    st.m = pl;
  }
  const float a = exp2f(pl - st.m);
  st.l += a;
  st.a.x = fmaf(a, vs.x, st.a.x);
  st.a.y = fmaf(a, vs.y, st.a.y);
  st.a.z = fmaf(a, vs.z, st.a.z);
  st.a.w = fmaf(a, vs.w, st.a.w);
}

__device__ __forceinline__ void sm_merge(SMState& d, const SMState& s) {
  const float mn = fmaxf(d.m, s.m);
  const float s1 = exp2f(d.m - mn);
  const float s2 = exp2f(s.m - mn);
  d.l = d.l * s1 + s.l * s2;
  d.a.x = d.a.x * s1 + s.a.x * s2;
  d.a.y = d.a.y * s1 + s.a.y * s2;
  d.a.z = d.a.z * s1 + s.a.z * s2;
  d.a.w = d.a.w * s1 + s.a.w * s2;
  d.m = mn;
}

__device__ __forceinline__ void sm_merge_xor(SMState& d, int off) {
  SMState s;
  s.m = __shfl_xor(d.m, off, 64);
  s.l = __shfl_xor(d.l, off, 64);
  s.a.x = __shfl_xor(d.a.x, off, 64);
  s.a.y = __shfl_xor(d.a.y, off, 64);
  s.a.z = __shfl_xor(d.a.z, off, 64);
  s.a.w = __shfl_xor(d.a.w, off, 64);
  sm_merge(d, s);
}

// ---------------------------------------------------------------------------
// Kernel C: per-node segmented online-softmax aggregation, BOTH batches per
// wave. 4 groups of 16 lanes; per group 2 ILP states x 2 batches. Per
// iteration all 8 row-loads are issued BEFORE any (branchy) compute.
// hk fp16 (pre-scaled to exp2 domain) via v_dot2_f32_f16; hv bf16.
// ---------------------------------------------------------------------------
__global__ __launch_bounds__(256) void aggregate_kernel(
    const unsigned short* __restrict__ hkv, const int* __restrict__ src,
    const int* __restrict__ row_ptr, float* __restrict__ out, int N) {
  const int node = blockIdx.x * 4 + (threadIdx.x >> 6);
  const int lane = threadIdx.x & 63;
  if (node >= N) return;
  const unsigned short* hb0 = hkv;
  const unsigned short* hb1 = hkv + (size_t)N * ROWH;

  const int li = lane & 15;  // dim-quad index (uint2 granule)
  const int g = lane >> 4;   // edge group

  const uint2 kd0 = reinterpret_cast<const uint2*>(hb0 + (size_t)node * ROWH)[li];
  const uint2 kd1 = reinterpret_cast<const uint2*>(hb1 + (size_t)node * ROWH)[li];
  const int e0 = row_ptr[node];
  const int e1 = row_ptr[node + 1];

  SMState A0 = {-FLT_MAX, 0.f, {0.f, 0.f, 0.f, 0.f}};
  SMState B0 = A0, A1 = A0, B1 = A0;

  int e = e0 + g;
  for (; e + 4 < e1; e += 8) {
    const int sA = src[e];
    const int sB = src[e + 4];
    const uint2* rA0 = reinterpret_cast<const uint2*>(hb0 + (size_t)sA * ROWH);
    const uint2* rA1 = reinterpret_cast<const uint2*>(hb1 + (size_t)sA * ROWH);
    const uint2* rB0 = reinterpret_cast<const uint2*>(hb0 + (size_t)sB * ROWH);
    const uint2* rB1 = reinterpret_cast<const uint2*>(hb1 + (size_t)sB * ROWH);
    const uint2 kA0 = rA0[li], vA0 = rA0[16 + li];
    const uint2 kA1 = rA1[li], vA1 = rA1[16 + li];
    const uint2 kB0 = rB0[li], vB0 = rB0[16 + li];
    const uint2 kB1 = rB1[li], vB1 = rB1[16 + li];

    const float plA0 = rowsum16(hdot4(kA0, kd0));
    const float plA1 = rowsum16(hdot4(kA1, kd1));
    const float plB0 = rowsum16(hdot4(kB0, kd0));
    const float plB1 = rowsum16(hdot4(kB1, kd1));

    sm_update(A0, plA0, unpack_bf4(vA0));
    sm_update(A1, plA1, unpack_bf4(vA1));
    sm_update(B0, plB0, unpack_bf4(vB0));
    sm_update(B1, plB1, unpack_bf4(vB1));
  }
  if (e < e1) {
    const int sA = src[e];
    const uint2* rA0 = reinterpret_cast<const uint2*>(hb0 + (size_t)sA * ROWH);
    const uint2* rA1 = reinterpret_cast<const uint2*>(hb1 + (size_t)sA * ROWH);
    const uint2 kA0 = rA0[li], vA0 = rA0[16 + li];
    const uint2 kA1 = rA1[li], vA1 = rA1[16 + li];
    const float plA0 = rowsum16(hdot4(kA0, kd0));
    const float plA1 = rowsum16(hdot4(kA1, kd1));
    sm_update(A0, plA0, unpack_bf4(vA0));
    sm_update(A1, plA1, unpack_bf4(vA1));
  }

  sm_merge(A0, B0);
  sm_merge(A1, B1);
  sm_merge_xor(A0, 16); sm_merge_xor(A0, 32);
  sm_merge_xor(A1, 16); sm_merge_xor(A1, 32);

  if (lane < 16) {
#pragma unroll
    for (int b = 0; b < 2; ++b) {
      const SMState& S = b ? A1 : A0;
      const float denom = (S.l == 0.f) ? 1.f : S.l;
      float4 o;
      o.x = S.a.x / denom; o.y = S.a.y / denom;
      o.z = S.a.z / denom; o.w = S.a.w / denom;
      o.x = (o.x >= 0.f) ? o.x : NEG_SLOPE * o.x;
      o.y = (o.y >= 0.f) ? o.y : NEG_SLOPE * o.y;
      o.z = (o.z >= 0.f) ? o.z : NEG_SLOPE * o.z;
      o.w = (o.w >= 0.f) ? o.w : NEG_SLOPE * o.w;
      *reinterpret_cast<float4*>(out + ((size_t)b * N + node) * D_OUT + 4 * lane) = o;
    }
  }
}

// ---------------------------------------------------------------------------
extern "C" void kernel_launch(void* const* d_in, const int* in_sizes, int n_in,
                              void* d_out, int out_size, void* d_ws,
                              size_t ws_size, hipStream_t stream) {
  const float* X_key   = (const float*)d_in[0];
  const float* X_value = (const float*)d_in[1];
  const float* Wk      = (const float*)d_in[2];
  const float* bk      = (const float*)d_in[3];
  const float* Wv      = (const float*)d_in[4];
  const float* bv      = (const float*)d_in[5];
  const int*   src     = (const int*)d_in[6];
  const int*   dst     = (const int*)d_in[7];
  float* out = (float*)d_out;

  const int B = 2;
  const int R = in_sizes[0] / D_IN;  // B*N rows
  const int N = R / B;
  const int E = in_sizes[6];

  // workspace: bfrag 32KB (16B-aligned) | hkv ushort[R][128] | row_ptr
  _Float16* bfrag = (_Float16*)d_ws;
  unsigned short* hkv = (unsigned short*)((char*)d_ws + 32768);
  int* row_ptr = (int*)(hkv + (size_t)R * ROWH);

  const int blocksB = (N + 1 + 255) / 256;
  hipLaunchKernelGGL(rowptr_kernel, dim3(blocksB), dim3(256), 0, stream,
                     dst, E, N, row_ptr);
  hipLaunchKernelGGL(bfrag_kernel, dim3(8), dim3(256), 0, stream,
                     Wk, Wv, bfrag);
  const int wavesPerMat = (R + 15) / 16;
  const int nblk = (wavesPerMat + 3) / 4;
  hipLaunchKernelGGL(linear_mfma_kernel, dim3(2 * nblk), dim3(256), 0, stream,
                     X_key, X_value, Wk, bk, Wv, bv, bfrag, hkv, R, nblk);
  const int blocksC = (N + 3) / 4;  // one wave per node, both batches
  hipLaunchKernelGGL(aggregate_kernel, dim3(blocksC), dim3(256), 0, stream,
                     hkv, src, row_ptr, out, N);
}